// Round 11
// baseline (182.188 us; speedup 1.0000x reference)
//
#include <hip/hip_runtime.h>

// N=64, T=96, F=32, ND=8, D=128. Output = concat( y (N,T,F)=196608 f32, att (F,F)=1024 f32 ).
#define SQKD 0.08838834764831845f  // 1/sqrt(128)

typedef __attribute__((ext_vector_type(8))) short short8;   // 8 bf16 = 4 VGPRs (MFMA A/B frag)
typedef __attribute__((ext_vector_type(4))) float f32x4;    // MFMA C/D frag

__device__ __forceinline__ unsigned short rne_bf16(float f) {
    unsigned u = __float_as_uint(f);
    return (unsigned short)((u + 0x7FFFu + ((u >> 16) & 1u)) >> 16);
}
// Split fp32 into bf16 hi + bf16 lo (RNE): f ~= hi + lo with ~2^-16 rel error.
__device__ __forceinline__ void bf16split(float f, unsigned short& hi, unsigned short& lo) {
    hi = rne_bf16(f);
    float fl = f - __uint_as_float(((unsigned)hi) << 16);
    lo = rne_bf16(fl);
}

// ---------------------------------------------------------------------------
// K0 prep (128 blocks):
//  0..63   : split x -> Ahi/Alo[(f*64+n)][t]
//  64..79  : split+transpose Wq/Wk base -> Wth/Wtl[(w*128+d)][t] (Wq scaled)
//  80..111 : w1 -> split w1h/w1l
//  112..127: w3q[dout][kh*128+d] = bf16(w3[dout][d*8+kh])
// ---------------------------------------------------------------------------
__global__ __launch_bounds__(256) void k_prep(
    const float* __restrict__ x, const float* __restrict__ Wq,
    const float* __restrict__ Wk,
    const float* __restrict__ w1, const float* __restrict__ w3,
    unsigned short* __restrict__ Ahi, unsigned short* __restrict__ Alo,
    unsigned short* __restrict__ Wth, unsigned short* __restrict__ Wtl,
    unsigned short* __restrict__ w1h, unsigned short* __restrict__ w1l,
    unsigned short* __restrict__ w3q)
{
    __shared__ float s_ws[96 * 129];
    const int tid = threadIdx.x;
    const int bid = blockIdx.x;
    if (bid < 64) {                      // x-split, block = n
        const int n = bid;
        for (int e = tid; e < 3072; e += 256)        // e = t*32+f, coalesced read
            s_ws[(e >> 5) * 33 + (e & 31)] = x[n * 3072 + e];
        __syncthreads();
        for (int o = tid; o < 3072; o += 256) {      // o = f*96+t
            const int f = o / 96, t = o - f * 96;
            float v = s_ws[t * 33 + f];
            unsigned short h, l; bf16split(v, h, l);
            Ahi[f * 6144 + n * 96 + t] = h;
            Alo[f * 6144 + n * 96 + t] = l;
        }
    } else if (bid < 80) {               // W-split, block = (sel,kh), sel in {0,1}
        const int w = bid - 64;          // 0..15
        const int sel = w >> 3;
        const int kh = w & 7;
        const float* src = (sel == 0 ? Wq : Wk) + kh * 12288;
        for (int e = tid; e < 12288; e += 256)       // e = t*128+d
            s_ws[(e >> 7) * 129 + (e & 127)] = src[e];
        __syncthreads();
        const float sc = (sel == 0) ? SQKD : 1.0f;
        for (int o = tid; o < 12288; o += 256) {     // o = d*96+t
            const int d = o / 96, t = o - d * 96;
            float v = s_ws[t * 129 + d] * sc;
            unsigned short h, l; bf16split(v, h, l);
            Wth[w * 12288 + o] = h;
            Wtl[w * 12288 + o] = l;
        }
    } else if (bid < 112) {              // w1 -> hi/lo split, flat
        const int base = (bid - 80) * 8192;
#pragma unroll
        for (int it = 0; it < 32; ++it) {
            const int i = base + it * 256 + tid;
            unsigned short h, l; bf16split(w1[i], h, l);
            w1h[i] = h; w1l[i] = l;
        }
    } else {                             // w3 permute -> bf16
        const int base = (bid - 112) * 8192;
#pragma unroll
        for (int it = 0; it < 32; ++it) {
            const int o = base + it * 256 + tid;     // o = dout*1024 + kh*128 + d
            const int dout = o >> 10, kk = o & 1023;
            const int kh = kk >> 7, d = kk & 127;
            w3q[o] = rne_bf16(w3[dout * 1024 + d * 8 + kh]);
        }
    }
}

// ---------------------------------------------------------------------------
// K0b (9 blocks): folds w3 through Wv (Z = A@WZ + bzc computed in k_qkvg).
//  blocks 0..7: WZ[dout-tile16][t] = sum_{kh,d} w3q[dout][kh*128+d]*Wv[kh][t][d]
//               waves split the d-chunks; cross-wave LDS reduction at the end.
//  block 8    : bzc[j][dout] = sum_{kh,d} bv[(j*8+kh)][d]*w3q[dout][kh*128+d]
// ---------------------------------------------------------------------------
__global__ __launch_bounds__(256) void k_wz(
    const float* __restrict__ Wv, const float* __restrict__ bv,
    const unsigned short* __restrict__ w3q,
    unsigned short* __restrict__ WZth, unsigned short* __restrict__ WZtl,
    float* __restrict__ bzc)
{
    __shared__ __align__(16) char smem[51200];
    const int tid = threadIdx.x;
    const int lane = tid & 63, wid = tid >> 6;
    const int quad = lane >> 4, col = lane & 15;
    const int bid = blockIdx.x;

    if (bid < 8) {                      // WZ tile: dout in [bid*16, bid*16+16)
        unsigned short* usB = (unsigned short*)smem;          // 96*136 ush = 26.1 KB
        float* red = (float*)(smem + 26624);                  // 4*1536 f32 = 24 KB
        const int dout0 = bid * 16;
        f32x4 acc[6];
#pragma unroll
        for (int nt = 0; nt < 6; ++nt)
#pragma unroll
            for (int r = 0; r < 4; ++r) acc[nt][r] = 0.f;

        for (int kh = 0; kh < 8; ++kh) {
            __syncthreads();
            // stage B = bf16(Wv[kh]) : 96 t-rows x 128 d (1536 granules)
#pragma unroll
            for (int it = 0; it < 6; ++it) {
                const int idx = it * 256 + tid;
                const int t = idx >> 4, c = idx & 15;
                const float* src = Wv + kh * 12288 + t * 128 + c * 8;
                short8 v;
#pragma unroll
                for (int j = 0; j < 8; ++j) v[j] = (short)rne_bf16(src[j]);
                *(short8*)(usB + t * 136 + c * 8) = v;
            }
            __syncthreads();
            // wave wid owns d-chunk [wid*32, wid*32+32)
            short8 a = *(const short8*)(w3q + (dout0 + col) * 1024 + kh * 128 + wid * 32 + quad * 8);
#pragma unroll
            for (int nt = 0; nt < 6; ++nt) {
                short8 b = *(const short8*)(usB + (nt * 16 + col) * 136 + wid * 32 + quad * 8);
                acc[nt] = __builtin_amdgcn_mfma_f32_16x16x32_bf16(a, b, acc[nt], 0, 0, 0);
            }
        }
        // cross-wave reduction of the 16x96 tile
#pragma unroll
        for (int nt = 0; nt < 6; ++nt)
#pragma unroll
            for (int r = 0; r < 4; ++r)
                red[wid * 1536 + (quad * 4 + r) * 96 + nt * 16 + col] = acc[nt][r];
        __syncthreads();
#pragma unroll
        for (int it = 0; it < 6; ++it) {
            const int el = it * 256 + tid;           // el = dl*96 + t
            float s = red[el] + red[1536 + el] + red[3072 + el] + red[4608 + el];
            const int dl = el / 96, t = el - dl * 96;
            unsigned short h, l; bf16split(s, h, l);
            WZth[(dout0 + dl) * 96 + t] = h;
            WZtl[(dout0 + dl) * 96 + t] = l;
        }
    } else {                            // bzc: 32 j x 128 dout
        unsigned short* sB  = (unsigned short*)smem;          // 128*136 = 34.8 KB
        unsigned short* sA2 = (unsigned short*)(smem + 34816);// 32*136  = 8.7 KB
        f32x4 acc[2][2];
#pragma unroll
        for (int mt = 0; mt < 2; ++mt)
#pragma unroll
            for (int nt = 0; nt < 2; ++nt)
#pragma unroll
                for (int r = 0; r < 4; ++r) acc[mt][nt][r] = 0.f;

        for (int kh = 0; kh < 8; ++kh) {
            __syncthreads();
#pragma unroll
            for (int it = 0; it < 2; ++it) {         // A = bf16(bv) 32x128
                const int idx = it * 256 + tid;
                const int j = idx >> 4, c = idx & 15;
                const float* src = bv + (j * 8 + kh) * 128 + c * 8;
                short8 v;
#pragma unroll
                for (int jj = 0; jj < 8; ++jj) v[jj] = (short)rne_bf16(src[jj]);
                *(short8*)(sA2 + j * 136 + c * 8) = v;
            }
#pragma unroll
            for (int it = 0; it < 8; ++it) {         // B = w3q chunk 128x128
                const int idx = it * 256 + tid;
                const int dd = idx >> 4, c = idx & 15;
                *(short8*)(sB + dd * 136 + c * 8) =
                    *(const short8*)(w3q + dd * 1024 + kh * 128 + c * 8);
            }
            __syncthreads();
#pragma unroll
            for (int ks = 0; ks < 4; ++ks) {
                short8 a[2], b[2];
#pragma unroll
                for (int mt = 0; mt < 2; ++mt)
                    a[mt] = *(const short8*)(sA2 + (mt * 16 + col) * 136 + ks * 32 + quad * 8);
#pragma unroll
                for (int nt = 0; nt < 2; ++nt)
                    b[nt] = *(const short8*)(sB + ((wid * 2 + nt) * 16 + col) * 136 + ks * 32 + quad * 8);
#pragma unroll
                for (int mt = 0; mt < 2; ++mt)
#pragma unroll
                    for (int nt = 0; nt < 2; ++nt)
                        acc[mt][nt] = __builtin_amdgcn_mfma_f32_16x16x32_bf16(a[mt], b[nt], acc[mt][nt], 0, 0, 0);
            }
        }
#pragma unroll
        for (int mt = 0; mt < 2; ++mt)
#pragma unroll
            for (int nt = 0; nt < 2; ++nt)
#pragma unroll
                for (int r = 0; r < 4; ++r) {
                    const int j = mt * 16 + quad * 4 + r;
                    const int dout = (wid * 2 + nt) * 16 + col;
                    bzc[j * 128 + dout] = acc[mt][nt][r];
                }
    }
}

// ---------------------------------------------------------------------------
// K1: Q/K/Z via MFMA. grid (fb=32, nh=2, b24=17). b24<8: Q(kh), <16: K(kh),
// ==16: Z = A@WZ + bzc. 3-term bf16 split = fp32-accurate GEMM. Epilogue LDS
// round-trip -> coalesced stores. K written transposed (ktH/ktL).
// ---------------------------------------------------------------------------
__global__ __launch_bounds__(256) void k_qkvg(
    const unsigned short* __restrict__ Ahi, const unsigned short* __restrict__ Alo,
    const unsigned short* __restrict__ Wth, const unsigned short* __restrict__ Wtl,
    const unsigned short* __restrict__ WZth, const unsigned short* __restrict__ WZtl,
    const float* __restrict__ bq, const float* __restrict__ bk,
    const float* __restrict__ bzc,
    unsigned short* __restrict__ qhi, unsigned short* __restrict__ qlo,
    unsigned short* __restrict__ ktH, unsigned short* __restrict__ ktL,
    float* __restrict__ Z)
{
    __shared__ __align__(16) char smem[49152];
    unsigned short* sAh = (unsigned short*)smem;              // 64*96 ush = 12 KB
    unsigned short* sAl = (unsigned short*)(smem + 12288);
    unsigned short* sBh = (unsigned short*)(smem + 24576);
    unsigned short* sBl = (unsigned short*)(smem + 36864);
    float* Lt = (float*)smem;                                  // 64*65 f32 (reuse)

    const int tid = threadIdx.x;
    const int fb = blockIdx.x, nh = blockIdx.y, b24 = blockIdx.z;
    const int sel = (b24 < 8) ? 0 : (b24 < 16) ? 1 : 2;
    const int kh = b24 & 7;

    const unsigned short* gAh = Ahi + fb * 6144;
    const unsigned short* gAl = Alo + fb * 6144;
    const unsigned short* gBh = (sel == 2) ? (WZth + nh * 64 * 96)
                                           : (Wth + (b24 * 128 + nh * 64) * 96);
    const unsigned short* gBl = (sel == 2) ? (WZtl + nh * 64 * 96)
                                           : (Wtl + (b24 * 128 + nh * 64) * 96);
#pragma unroll
    for (int it = 0; it < 3; ++it) {
        const int off = (it * 256 + tid) * 8;
        *(short8*)(sAh + off) = *(const short8*)(gAh + off);
        *(short8*)(sAl + off) = *(const short8*)(gAl + off);
        *(short8*)(sBh + off) = *(const short8*)(gBh + off);
        *(short8*)(sBl + off) = *(const short8*)(gBl + off);
    }
    __syncthreads();

    const int lane = tid & 63, wid = tid >> 6;
    const int quad = lane >> 4, col = lane & 15;
    f32x4 acc[4];
#pragma unroll
    for (int nt = 0; nt < 4; ++nt)
#pragma unroll
        for (int r = 0; r < 4; ++r) acc[nt][r] = 0.f;

#pragma unroll
    for (int ks = 0; ks < 3; ++ks) {
        const int ko = ks * 32 + quad * 8;
        short8 ah = *(const short8*)(sAh + (wid * 16 + col) * 96 + ko);
        short8 al = *(const short8*)(sAl + (wid * 16 + col) * 96 + ko);
#pragma unroll
        for (int nt = 0; nt < 4; ++nt) {
            short8 bh = *(const short8*)(sBh + (nt * 16 + col) * 96 + ko);
            short8 bl = *(const short8*)(sBl + (nt * 16 + col) * 96 + ko);
            acc[nt] = __builtin_amdgcn_mfma_f32_16x16x32_bf16(ah, bh, acc[nt], 0, 0, 0);
            acc[nt] = __builtin_amdgcn_mfma_f32_16x16x32_bf16(al, bh, acc[nt], 0, 0, 0);
            acc[nt] = __builtin_amdgcn_mfma_f32_16x16x32_bf16(ah, bl, acc[nt], 0, 0, 0);
        }
    }

    // epilogue: acc -> LDS f32 (stride 65), re-read coalesced
    const int b = fb * 8 + kh;
    __syncthreads();                    // staging reads complete before overwrite
#pragma unroll
    for (int nt = 0; nt < 4; ++nt) {
        const int dl = nt * 16 + col;
        float bb = 0.f;
        if (sel == 0)      bb = bq[b * 128 + nh * 64 + dl] * SQKD;
        else if (sel == 1) bb = bk[b * 128 + nh * 64 + dl];
#pragma unroll
        for (int r = 0; r < 4; ++r)
            Lt[(wid * 16 + quad * 4 + r) * 65 + dl] = acc[nt][r] + bb;
    }
    __syncthreads();

    if (sel == 1) {                     // transposed K output
        const int dd = tid >> 2, mg = (tid & 3) * 16;
        short8 h0, h1, l0, l1;
#pragma unroll
        for (int j = 0; j < 8; ++j) {
            unsigned short h, l;
            bf16split(Lt[(mg + j) * 65 + dd], h, l);
            h0[j] = (short)h; l0[j] = (short)l;
        }
#pragma unroll
        for (int j = 0; j < 8; ++j) {
            unsigned short h, l;
            bf16split(Lt[(mg + 8 + j) * 65 + dd], h, l);
            h1[j] = (short)h; l1[j] = (short)l;
        }
        const long base = ((long)b * 128 + nh * 64 + dd) * 64 + mg;
        *(short8*)(ktH + base) = h0; *(short8*)(ktH + base + 8) = h1;
        *(short8*)(ktL + base) = l0; *(short8*)(ktL + base + 8) = l1;
    } else if (sel == 0) {
        const int n = tid >> 2, dg = (tid & 3) * 16;
        const int o = (b * 64 + n) * 128 + nh * 64 + dg;
        short8 h0, h1, l0, l1;
#pragma unroll
        for (int j = 0; j < 8; ++j) {
            unsigned short h, l;
            bf16split(Lt[n * 65 + dg + j], h, l);
            h0[j] = (short)h; l0[j] = (short)l;
        }
#pragma unroll
        for (int j = 0; j < 8; ++j) {
            unsigned short h, l;
            bf16split(Lt[n * 65 + dg + 8 + j], h, l);
            h1[j] = (short)h; l1[j] = (short)l;
        }
        *(short8*)(qhi + o) = h0; *(short8*)(qhi + o + 8) = h1;
        *(short8*)(qlo + o) = l0; *(short8*)(qlo + o + 8) = l1;
    } else {                            // Z = Lt + bzc, fp32
        const int n = tid >> 2, dg = (tid & 3) * 16;
        float* Zr = Z + (fb * 64 + n) * 128 + nh * 64 + dg;
        const float* bz = bzc + fb * 128 + nh * 64 + dg;
#pragma unroll
        for (int q4 = 0; q4 < 4; ++q4) {
            f32x4 v;
            v.x = Lt[n * 65 + dg + q4 * 4 + 0] + bz[q4 * 4 + 0];
            v.y = Lt[n * 65 + dg + q4 * 4 + 1] + bz[q4 * 4 + 1];
            v.z = Lt[n * 65 + dg + q4 * 4 + 2] + bz[q4 * 4 + 2];
            v.w = Lt[n * 65 + dg + q4 * 4 + 3] + bz[q4 * 4 + 3];
            *(f32x4*)(Zr + q4 * 4) = v;
        }
    }
}

// ---------------------------------------------------------------------------
// K2a: T_g[e][n][d] = sum_m w1[e][kh][n][m] * K_g[kh][m][d].
// grid (256 = g*8+kh, pass=2): 512 blocks, wave = e = wid*2+pass.
// Block (0,0) also zeroes He (poisoned workspace; k_he accumulates atomically).
// ---------------------------------------------------------------------------
__global__ __launch_bounds__(256) void k_t(
    const unsigned short* __restrict__ ktH, const unsigned short* __restrict__ ktL,
    const unsigned short* __restrict__ w1h, const unsigned short* __restrict__ w1l,
    unsigned short* __restrict__ Tb, float* __restrict__ He)
{
    __shared__ __align__(16) unsigned short sH[128 * 72];   // 18 KB
    __shared__ __align__(16) unsigned short sL[128 * 72];
    const int tid = threadIdx.x;
    const int g = blockIdx.x >> 3, kh = blockIdx.x & 7;
    const int pass = blockIdx.y;
    const int lane = tid & 63, wid = tid >> 6;
    const int quad = lane >> 4, col = lane & 15;

    if (blockIdx.x == 0 && blockIdx.y == 0) {
#pragma unroll
        for (int i = 0; i < 32; ++i) He[i * 256 + tid] = 0.f;
    }

    {   // stage K^T tile: 128 d-rows x 64 m
        const unsigned short* gH = ktH + (long)(g * 8 + kh) * 8192;
        const unsigned short* gL = ktL + (long)(g * 8 + kh) * 8192;
#pragma unroll
        for (int it = 0; it < 4; ++it) {
            const int idx = it * 256 + tid;
            const int d = idx >> 3, gr = idx & 7;
            *(short8*)(sH + d * 72 + gr * 8) = *(const short8*)(gH + idx * 8);
            *(short8*)(sL + d * 72 + gr * 8) = *(const short8*)(gL + idx * 8);
        }
    }
    __syncthreads();

    const int e = wid * 2 + pass;
    f32x4 acc[4][8];
#pragma unroll
    for (int mt = 0; mt < 4; ++mt)
#pragma unroll
        for (int nt = 0; nt < 8; ++nt)
#pragma unroll
            for (int r = 0; r < 4; ++r) acc[mt][nt][r] = 0.f;

    const unsigned short* w1he = w1h + e * 32768 + kh * 4096;
    const unsigned short* w1le = w1l + e * 32768 + kh * 4096;
#pragma unroll
    for (int ks = 0; ks < 2; ++ks) {
        short8 ah[4], al[4];
#pragma unroll
        for (int mt = 0; mt < 4; ++mt) {
            const int off = (mt * 16 + col) * 64 + ks * 32 + quad * 8;
            ah[mt] = *(const short8*)(w1he + off);
            al[mt] = *(const short8*)(w1le + off);
        }
#pragma unroll
        for (int nt = 0; nt < 8; ++nt) {
            const int off = (nt * 16 + col) * 72 + ks * 32 + quad * 8;
            short8 bh = *(const short8*)(sH + off);
            short8 bl = *(const short8*)(sL + off);
#pragma unroll
            for (int mt = 0; mt < 4; ++mt) {
                acc[mt][nt] = __builtin_amdgcn_mfma_f32_16x16x32_bf16(ah[mt], bh, acc[mt][nt], 0, 0, 0);
                acc[mt][nt] = __builtin_amdgcn_mfma_f32_16x16x32_bf16(al[mt], bh, acc[mt][nt], 0, 0, 0);
                acc[mt][nt] = __builtin_amdgcn_mfma_f32_16x16x32_bf16(ah[mt], bl, acc[mt][nt], 0, 0, 0);
            }
        }
    }

    unsigned short* To = Tb + (long)(g * 8 + e) * 65536 + kh * 8192;
#pragma unroll
    for (int mt = 0; mt < 4; ++mt)
#pragma unroll
        for (int nt = 0; nt < 8; ++nt)
#pragma unroll
            for (int r = 0; r < 4; ++r) {
                const int n = mt * 16 + quad * 4 + r;
                const int d = nt * 16 + col;
                To[n * 128 + d] = rne_bf16(acc[mt][nt][r]);
            }
}

// ---------------------------------------------------------------------------
// K2b: he[(g,e),f] = sum_K T[(g,e)][K] * Q[f][K].  256 K-slice blocks x 512.
// Pure streaming MFMA; partials accumulated straight into He via atomicAdd
// (He zeroed by k_t; no k_hred launch).
// ---------------------------------------------------------------------------
__global__ __launch_bounds__(512) void k_he(
    const unsigned short* __restrict__ Tb,
    const unsigned short* __restrict__ qhi, const unsigned short* __restrict__ qlo,
    float* __restrict__ He)
{
    const int tid = threadIdx.x;
    const int s = blockIdx.x;
    const long K0 = (long)s * 256;
    const int lane = tid & 63, wid = tid >> 6;     // 0..7
    const int quad = lane >> 4, col = lane & 15;

    f32x4 acc[2][2];
#pragma unroll
    for (int mt = 0; mt < 2; ++mt)
#pragma unroll
        for (int nt = 0; nt < 2; ++nt)
#pragma unroll
            for (int r = 0; r < 4; ++r) acc[mt][nt][r] = 0.f;

    for (int ks = 0; ks < 8; ++ks) {
        const long ko = K0 + ks * 32 + quad * 8;
        short8 t[2];
#pragma unroll
        for (int mt = 0; mt < 2; ++mt) {
            const int ge = (wid * 2 + mt) * 16 + col;
            t[mt] = *(const short8*)(Tb + (long)ge * 65536 + ko);
        }
#pragma unroll
        for (int nt = 0; nt < 2; ++nt) {
            const int f = nt * 16 + col;
            short8 qh = *(const short8*)(qhi + (long)f * 65536 + ko);
            short8 ql = *(const short8*)(qlo + (long)f * 65536 + ko);
#pragma unroll
            for (int mt = 0; mt < 2; ++mt) {
                acc[mt][nt] = __builtin_amdgcn_mfma_f32_16x16x32_bf16(t[mt], qh, acc[mt][nt], 0, 0, 0);
                acc[mt][nt] = __builtin_amdgcn_mfma_f32_16x16x32_bf16(t[mt], ql, acc[mt][nt], 0, 0, 0);
            }
        }
    }

#pragma unroll
    for (int mt = 0; mt < 2; ++mt)
#pragma unroll
        for (int nt = 0; nt < 2; ++nt)
#pragma unroll
            for (int r = 0; r < 4; ++r) {
                const int ge = (wid * 2 + mt) * 16 + quad * 4 + r;
                const int f = nt * 16 + col;
                atomicAdd(&He[ge * 32 + f], acc[mt][nt][r]);
            }
}

// ---------------------------------------------------------------------------
// K5: grid (n=64, th=4). Fused: logits+softmax from He (per-block, L2-hot;
// block (0,0) writes att output), then y1 = relu(b3 + att@Z), out = y1@w4^T+b4.
// All phase-2 operands in LDS. 24 t per block -> 256 blocks (1/CU).
// ---------------------------------------------------------------------------
__global__ __launch_bounds__(256) void k_y(
    const float* __restrict__ Z, const float* __restrict__ He,
    const float* __restrict__ b1, const float* __restrict__ w2,
    const float* __restrict__ b2, const float* __restrict__ b3,
    const float* __restrict__ w4, const float* __restrict__ b4,
    float* __restrict__ out, float* __restrict__ attOut)
{
    __shared__ __align__(16) float Zs[32 * 128];
    __shared__ float atts[1024];
    __shared__ __align__(16) float y1s[32 * 132];    // also holds logits temporarily
    __shared__ __align__(16) float w4s[24 * 132];
    const int n = blockIdx.x;
    const int t0 = blockIdx.y * 24;
    const int tid = threadIdx.x;

#pragma unroll
    for (int it = 0; it < 4; ++it) {
        const int gdx = it * 256 + tid;
        const int j = gdx >> 5, c = gdx & 31;
        *(f32x4*)(Zs + j * 128 + c * 4) = *(const f32x4*)(Z + j * 8192 + n * 128 + c * 4);
    }
#pragma unroll
    for (int it = 0; it < 3; ++it) {     // stage w4 quarter: 24 rows x 32 f32x4
        const int gdx = it * 256 + tid;
        const int row = gdx >> 5, c = gdx & 31;
        *(f32x4*)(w4s + row * 132 + c * 4) = *(const f32x4*)(w4 + (t0 + row) * 128 + c * 4);
    }
    // logits -> y1s[0..1023] (reused as scratch)
    float* lgs = y1s;
#pragma unroll
    for (int it = 0; it < 4; ++it) {
        const int idx = it * 256 + tid;
        const int f = idx & 31, g = idx >> 5;
        float s = b2[0];
#pragma unroll
        for (int e = 0; e < 8; ++e)
            s += fmaxf(He[g * 256 + e * 32 + f] + b1[e], 0.f) * w2[e];
        lgs[f * 32 + g] = s;
    }
    __syncthreads();
    {   // softmax over g: 32-lane shuffle groups
        const int f8 = tid >> 5, g = tid & 31;
#pragma unroll
        for (int fi = 0; fi < 4; ++fi) {
            const int f = f8 * 4 + fi;
            float s = lgs[f * 32 + g];
            float mx = s;
#pragma unroll
            for (int m = 16; m >= 1; m >>= 1) mx = fmaxf(mx, __shfl_xor(mx, m));
            float ex = expf(s - mx);
            float sum = ex;
#pragma unroll
            for (int m = 16; m >= 1; m >>= 1) sum += __shfl_xor(sum, m);
            atts[f * 32 + g] = ex / sum;
        }
    }
    __syncthreads();
    if (blockIdx.x == 0 && blockIdx.y == 0) {
#pragma unroll
        for (int it = 0; it < 4; ++it) {
            const int idx = it * 256 + tid;
            attOut[idx] = atts[idx];
        }
    }

    {   // phase 1: thread = (f, dout/16-group); overwrites y1s (lgs dead)
        const int ff = tid >> 3, l8 = tid & 7;
        f32x4 a4[4];
#pragma unroll
        for (int v = 0; v < 4; ++v) a4[v] = *(const f32x4*)(b3 + l8 * 16 + v * 4);
        for (int j = 0; j < 32; ++j) {
            const float a = atts[ff * 32 + j];
#pragma unroll
            for (int v = 0; v < 4; ++v) {
                f32x4 z = *(const f32x4*)(Zs + j * 128 + l8 * 16 + v * 4);
                a4[v].x += a * z.x; a4[v].y += a * z.y;
                a4[v].z += a * z.z; a4[v].w += a * z.w;
            }
        }
        __syncthreads();                 // all lgs reads done before overwrite
#pragma unroll
        for (int v = 0; v < 4; ++v) {
            f32x4 r;
            r.x = fmaxf(a4[v].x, 0.f); r.y = fmaxf(a4[v].y, 0.f);
            r.z = fmaxf(a4[v].z, 0.f); r.w = fmaxf(a4[v].w, 0.f);
            *(f32x4*)(y1s + ff * 132 + l8 * 16 + v * 4) = r;
        }
    }
    __syncthreads();

#pragma unroll
    for (int it = 0; it < 3; ++it) {     // phase 2: o = tl*32+f over 24 t's
        const int o = it * 256 + tid;
        const int tl = o >> 5, ff = o & 31;
        float s = b4[t0 + tl];
        const float* w4r = w4s + tl * 132;
        const float* y1r = y1s + ff * 132;
#pragma unroll 8
        for (int d4 = 0; d4 < 32; ++d4) {
            f32x4 w = *(const f32x4*)(w4r + d4 * 4);
            f32x4 y = *(const f32x4*)(y1r + d4 * 4);
            s += y.x * w.x + y.y * w.y + y.z * w.z + y.w * w.w;
        }
        out[n * 3072 + (t0 + tl) * 32 + ff] = s;
    }
}

// ---------------------------------------------------------------------------
extern "C" void kernel_launch(void* const* d_in, const int* in_sizes, int n_in,
                              void* d_out, int out_size, void* d_ws, size_t ws_size,
                              hipStream_t stream)
{
    const float* x  = (const float*)d_in[0];
    const float* Wq = (const float*)d_in[1];
    const float* Wk = (const float*)d_in[2];
    const float* Wv = (const float*)d_in[3];
    const float* bq = (const float*)d_in[4];
    const float* bk = (const float*)d_in[5];
    const float* bv = (const float*)d_in[6];
    const float* w1 = (const float*)d_in[7];
    const float* b1 = (const float*)d_in[8];
    const float* w2 = (const float*)d_in[9];
    const float* b2 = (const float*)d_in[10];
    const float* w3 = (const float*)d_in[11];
    const float* b3 = (const float*)d_in[12];
    const float* w4 = (const float*)d_in[13];
    const float* b4 = (const float*)d_in[14];

    float* out = (float*)d_out;
    char*  wb  = (char*)d_ws;
    unsigned short* qhi  = (unsigned short*)(wb + 0x0000000);   // 4 MB
    unsigned short* qlo  = (unsigned short*)(wb + 0x0400000);   // 4 MB
    unsigned short* ktH  = (unsigned short*)(wb + 0x0800000);   // 4 MB
    unsigned short* ktL  = (unsigned short*)(wb + 0x0C00000);   // 4 MB
    unsigned short* Tb   = (unsigned short*)(wb + 0x1000000);   // 32 MB
    float*          He   = (float*)        (wb + 0x3000000);    // 32 KB
    unsigned short* Ahi  = (unsigned short*)(wb + 0x3010000);   // 384 KB
    unsigned short* Alo  = (unsigned short*)(wb + 0x3070000);   // 384 KB
    unsigned short* Wth  = (unsigned short*)(wb + 0x30D0000);   // 384 KB (16 planes)
    unsigned short* Wtl  = (unsigned short*)(wb + 0x3130000);   // 384 KB
    unsigned short* w1h  = (unsigned short*)(wb + 0x3190000);   // 512 KB
    unsigned short* w1l  = (unsigned short*)(wb + 0x3210000);   // 512 KB
    unsigned short* w3q  = (unsigned short*)(wb + 0x3290000);   // 256 KB
    unsigned short* WZth = (unsigned short*)(wb + 0x32D0000);   // 24 KB
    unsigned short* WZtl = (unsigned short*)(wb + 0x32D8000);   // 24 KB
    float*          bzc  = (float*)        (wb + 0x32E0000);    // 16 KB
    float*          Zb   = (float*)        (wb + 0x32F0000);    // 1 MB (end ~54 MB)
    float* att = out + 196608;

    k_prep <<<128, 256, 0, stream>>>(x, Wq, Wk, w1, w3,
                                     Ahi, Alo, Wth, Wtl, w1h, w1l, w3q);
    k_wz   <<<9, 256, 0, stream>>>(Wv, bv, w3q, WZth, WZtl, bzc);
    k_qkvg <<<dim3(32, 2, 17), 256, 0, stream>>>(Ahi, Alo, Wth, Wtl, WZth, WZtl,
                                                 bq, bk, bzc, qhi, qlo, ktH, ktL, Zb);
    k_t    <<<dim3(256, 2), 256, 0, stream>>>(ktH, ktL, w1h, w1l, Tb, He);
    k_he   <<<256, 512, 0, stream>>>(Tb, qhi, qlo, He);
    k_y    <<<dim3(64, 4), 256, 0, stream>>>(Zb, He, b1, w2, b2, b3, w4, b4, out, att);
}

// Round 12
// 172.064 us; speedup vs baseline: 1.0588x; 1.0588x over previous
//
#include <hip/hip_runtime.h>

// N=64, T=96, F=32, ND=8, D=128. Output = concat( y (N,T,F)=196608 f32, att (F,F)=1024 f32 ).
#define SQKD 0.08838834764831845f  // 1/sqrt(128)

typedef __attribute__((ext_vector_type(8))) short short8;   // 8 bf16 = 4 VGPRs (MFMA A/B frag)
typedef __attribute__((ext_vector_type(4))) float f32x4;    // MFMA C/D frag

__device__ __forceinline__ unsigned short rne_bf16(float f) {
    unsigned u = __float_as_uint(f);
    return (unsigned short)((u + 0x7FFFu + ((u >> 16) & 1u)) >> 16);
}
// Split fp32 into bf16 hi + bf16 lo (RNE): f ~= hi + lo with ~2^-16 rel error.
__device__ __forceinline__ void bf16split(float f, unsigned short& hi, unsigned short& lo) {
    hi = rne_bf16(f);
    float fl = f - __uint_as_float(((unsigned)hi) << 16);
    lo = rne_bf16(fl);
}

// ---------------------------------------------------------------------------
// K0 prep:
//  blocks 0..63   : split x -> Ahi/Alo[(f*64+n)][t]
//  blocks 64..87  : split+transpose Wbase -> Wth/Wtl[(w*128+d)][t] (Wq scaled)
//  blocks 88..119 : w1 -> split w1h/w1l (flat, layout [e][kh*4096+n*64+m])
//  blocks 120..135: w3q[dout][kh*128+d] = bf16(w3[dout][d*8+kh])
// ---------------------------------------------------------------------------
__global__ __launch_bounds__(256) void k_prep(
    const float* __restrict__ x, const float* __restrict__ Wq,
    const float* __restrict__ Wk, const float* __restrict__ Wv,
    const float* __restrict__ w1, const float* __restrict__ w3,
    unsigned short* __restrict__ Ahi, unsigned short* __restrict__ Alo,
    unsigned short* __restrict__ Wth, unsigned short* __restrict__ Wtl,
    unsigned short* __restrict__ w1h, unsigned short* __restrict__ w1l,
    unsigned short* __restrict__ w3q)
{
    __shared__ float s_ws[96 * 129];
    const int tid = threadIdx.x;
    const int bid = blockIdx.x;
    if (bid < 64) {                      // x-split, block = n
        const int n = bid;
        for (int e = tid; e < 3072; e += 256)        // e = t*32+f, coalesced read
            s_ws[(e >> 5) * 33 + (e & 31)] = x[n * 3072 + e];
        __syncthreads();
        for (int o = tid; o < 3072; o += 256) {      // o = f*96+t
            const int f = o / 96, t = o - f * 96;
            float v = s_ws[t * 33 + f];
            unsigned short h, l; bf16split(v, h, l);
            Ahi[f * 6144 + n * 96 + t] = h;
            Alo[f * 6144 + n * 96 + t] = l;
        }
    } else if (bid < 88) {               // W-split, block = (sel,kh)
        const int w = bid - 64;          // 0..23
        const int sel = w >> 3;
        const int kh = w & 7;
        const float* src = (sel == 0 ? Wq : sel == 1 ? Wk : Wv) + kh * 12288;
        for (int e = tid; e < 12288; e += 256)       // e = t*128+d
            s_ws[(e >> 7) * 129 + (e & 127)] = src[e];
        __syncthreads();
        const float sc = (sel == 0) ? SQKD : 1.0f;
        for (int o = tid; o < 12288; o += 256) {     // o = d*96+t
            const int d = o / 96, t = o - d * 96;
            float v = s_ws[t * 129 + d] * sc;
            unsigned short h, l; bf16split(v, h, l);
            Wth[w * 12288 + o] = h;
            Wtl[w * 12288 + o] = l;
        }
    } else if (bid < 120) {              // w1 -> hi/lo split, flat
        const int base = (bid - 88) * 8192;
#pragma unroll
        for (int it = 0; it < 32; ++it) {
            const int i = base + it * 256 + tid;
            unsigned short h, l; bf16split(w1[i], h, l);
            w1h[i] = h; w1l[i] = l;
        }
    } else {                             // w3 permute -> bf16
        const int base = (bid - 120) * 8192;
#pragma unroll
        for (int it = 0; it < 32; ++it) {
            const int o = base + it * 256 + tid;     // o = dout*1024 + kh*128 + d
            const int dout = o >> 10, kk = o & 1023;
            const int kh = kk >> 7, d = kk & 127;
            w3q[o] = rne_bf16(w3[dout * 1024 + d * 8 + kh]);
        }
    }
}

// ---------------------------------------------------------------------------
// K1: QKV via MFMA. grid (fb=32, nh=2, b24=24: sel*8+kh). Per block:
// D[64n x 64d] = A[64 x 96] @ W[96 x 64], 3-term bf16 split = fp32-accurate.
// Epilogue LDS round-trip -> fully coalesced stores.
//  sel0: Q split hi/lo, layout [(f*8+kh)*64+n][d]
//  sel1: K split hi/lo TRANSPOSED: ktH/ktL[(g*8+kh)*128 + d][m]  (m = K row)
//  sel2: V single bf16 [(f*8+kh)*64+n][d]
// ---------------------------------------------------------------------------
__global__ __launch_bounds__(256) void k_qkvg(
    const unsigned short* __restrict__ Ahi, const unsigned short* __restrict__ Alo,
    const unsigned short* __restrict__ Wth, const unsigned short* __restrict__ Wtl,
    const float* __restrict__ bq, const float* __restrict__ bk, const float* __restrict__ bv,
    unsigned short* __restrict__ qhi, unsigned short* __restrict__ qlo,
    unsigned short* __restrict__ ktH, unsigned short* __restrict__ ktL,
    unsigned short* __restrict__ V16)
{
    __shared__ __align__(16) char smem[49152];
    unsigned short* sAh = (unsigned short*)smem;              // 64*96 ush = 12 KB
    unsigned short* sAl = (unsigned short*)(smem + 12288);
    unsigned short* sBh = (unsigned short*)(smem + 24576);
    unsigned short* sBl = (unsigned short*)(smem + 36864);
    float* Lt = (float*)smem;                                  // 64*65 f32 (reuse)

    const int tid = threadIdx.x;
    const int fb = blockIdx.x, nh = blockIdx.y, b24 = blockIdx.z;
    const int sel = b24 >> 3, kh = b24 & 7;

    const unsigned short* gAh = Ahi + fb * 6144;
    const unsigned short* gAl = Alo + fb * 6144;
    const unsigned short* gBh = Wth + (b24 * 128 + nh * 64) * 96;
    const unsigned short* gBl = Wtl + (b24 * 128 + nh * 64) * 96;
#pragma unroll
    for (int it = 0; it < 3; ++it) {
        const int off = (it * 256 + tid) * 8;
        *(short8*)(sAh + off) = *(const short8*)(gAh + off);
        *(short8*)(sAl + off) = *(const short8*)(gAl + off);
        *(short8*)(sBh + off) = *(const short8*)(gBh + off);
        *(short8*)(sBl + off) = *(const short8*)(gBl + off);
    }
    __syncthreads();

    const int lane = tid & 63, wid = tid >> 6;
    const int quad = lane >> 4, col = lane & 15;
    f32x4 acc[4];
#pragma unroll
    for (int nt = 0; nt < 4; ++nt)
#pragma unroll
        for (int r = 0; r < 4; ++r) acc[nt][r] = 0.f;

#pragma unroll
    for (int ks = 0; ks < 3; ++ks) {
        const int ko = ks * 32 + quad * 8;
        short8 ah = *(const short8*)(sAh + (wid * 16 + col) * 96 + ko);
        short8 al = *(const short8*)(sAl + (wid * 16 + col) * 96 + ko);
#pragma unroll
        for (int nt = 0; nt < 4; ++nt) {
            short8 bh = *(const short8*)(sBh + (nt * 16 + col) * 96 + ko);
            short8 bl = *(const short8*)(sBl + (nt * 16 + col) * 96 + ko);
            acc[nt] = __builtin_amdgcn_mfma_f32_16x16x32_bf16(ah, bh, acc[nt], 0, 0, 0);
            acc[nt] = __builtin_amdgcn_mfma_f32_16x16x32_bf16(al, bh, acc[nt], 0, 0, 0);
            acc[nt] = __builtin_amdgcn_mfma_f32_16x16x32_bf16(ah, bl, acc[nt], 0, 0, 0);
        }
    }

    // epilogue: acc -> LDS f32 (stride 65, conflict-free), re-read coalesced
    const int b = fb * 8 + kh;
    const float* bias = sel == 0 ? bq : sel == 1 ? bk : bv;
    const float bsc = (sel == 0) ? SQKD : 1.0f;
    __syncthreads();                    // staging reads complete before overwrite
#pragma unroll
    for (int nt = 0; nt < 4; ++nt) {
        const int dl = nt * 16 + col;
        const float bb = bias[b * 128 + nh * 64 + dl] * bsc;
#pragma unroll
        for (int r = 0; r < 4; ++r)
            Lt[(wid * 16 + quad * 4 + r) * 65 + dl] = acc[nt][r] + bb;
    }
    __syncthreads();

    if (sel == 1) {                     // transposed K output
        const int dd = tid >> 2, mg = (tid & 3) * 16;
        short8 h0, h1, l0, l1;
#pragma unroll
        for (int j = 0; j < 8; ++j) {
            unsigned short h, l;
            bf16split(Lt[(mg + j) * 65 + dd], h, l);
            h0[j] = (short)h; l0[j] = (short)l;
        }
#pragma unroll
        for (int j = 0; j < 8; ++j) {
            unsigned short h, l;
            bf16split(Lt[(mg + 8 + j) * 65 + dd], h, l);
            h1[j] = (short)h; l1[j] = (short)l;
        }
        const long base = ((long)b * 128 + nh * 64 + dd) * 64 + mg;
        *(short8*)(ktH + base) = h0; *(short8*)(ktH + base + 8) = h1;
        *(short8*)(ktL + base) = l0; *(short8*)(ktL + base + 8) = l1;
    } else {
        const int n = tid >> 2, dg = (tid & 3) * 16;
        const int o = (b * 64 + n) * 128 + nh * 64 + dg;
        if (sel == 0) {
            short8 h0, h1, l0, l1;
#pragma unroll
            for (int j = 0; j < 8; ++j) {
                unsigned short h, l;
                bf16split(Lt[n * 65 + dg + j], h, l);
                h0[j] = (short)h; l0[j] = (short)l;
            }
#pragma unroll
            for (int j = 0; j < 8; ++j) {
                unsigned short h, l;
                bf16split(Lt[n * 65 + dg + 8 + j], h, l);
                h1[j] = (short)h; l1[j] = (short)l;
            }
            *(short8*)(qhi + o) = h0; *(short8*)(qhi + o + 8) = h1;
            *(short8*)(qlo + o) = l0; *(short8*)(qlo + o + 8) = l1;
        } else {
            short8 v0, v1;
#pragma unroll
            for (int j = 0; j < 8; ++j) v0[j] = (short)rne_bf16(Lt[n * 65 + dg + j]);
#pragma unroll
            for (int j = 0; j < 8; ++j) v1[j] = (short)rne_bf16(Lt[n * 65 + dg + 8 + j]);
            *(short8*)(V16 + o) = v0; *(short8*)(V16 + o + 8) = v1;
        }
    }
}

// ---------------------------------------------------------------------------
// K2a: T_g[e][n][d] = sum_m w1[e][kh][n][m] * K_g[kh][m][d].
// grid (256 = g*8+kh, pass=2): 512 blocks, wave = e = wid*2+pass.
// ---------------------------------------------------------------------------
__global__ __launch_bounds__(256) void k_t(
    const unsigned short* __restrict__ ktH, const unsigned short* __restrict__ ktL,
    const unsigned short* __restrict__ w1h, const unsigned short* __restrict__ w1l,
    unsigned short* __restrict__ Tb)
{
    __shared__ __align__(16) unsigned short sH[128 * 72];   // 18 KB
    __shared__ __align__(16) unsigned short sL[128 * 72];
    const int tid = threadIdx.x;
    const int g = blockIdx.x >> 3, kh = blockIdx.x & 7;
    const int pass = blockIdx.y;
    const int lane = tid & 63, wid = tid >> 6;
    const int quad = lane >> 4, col = lane & 15;

    {   // stage K^T tile: 128 d-rows x 64 m
        const unsigned short* gH = ktH + (long)(g * 8 + kh) * 8192;
        const unsigned short* gL = ktL + (long)(g * 8 + kh) * 8192;
#pragma unroll
        for (int it = 0; it < 4; ++it) {
            const int idx = it * 256 + tid;
            const int d = idx >> 3, gr = idx & 7;
            *(short8*)(sH + d * 72 + gr * 8) = *(const short8*)(gH + idx * 8);
            *(short8*)(sL + d * 72 + gr * 8) = *(const short8*)(gL + idx * 8);
        }
    }
    __syncthreads();

    const int e = wid * 2 + pass;
    f32x4 acc[4][8];
#pragma unroll
    for (int mt = 0; mt < 4; ++mt)
#pragma unroll
        for (int nt = 0; nt < 8; ++nt)
#pragma unroll
            for (int r = 0; r < 4; ++r) acc[mt][nt][r] = 0.f;

    const unsigned short* w1he = w1h + e * 32768 + kh * 4096;
    const unsigned short* w1le = w1l + e * 32768 + kh * 4096;
#pragma unroll
    for (int ks = 0; ks < 2; ++ks) {
        short8 ah[4], al[4];
#pragma unroll
        for (int mt = 0; mt < 4; ++mt) {
            const int off = (mt * 16 + col) * 64 + ks * 32 + quad * 8;
            ah[mt] = *(const short8*)(w1he + off);
            al[mt] = *(const short8*)(w1le + off);
        }
#pragma unroll
        for (int nt = 0; nt < 8; ++nt) {
            const int off = (nt * 16 + col) * 72 + ks * 32 + quad * 8;
            short8 bh = *(const short8*)(sH + off);
            short8 bl = *(const short8*)(sL + off);
#pragma unroll
            for (int mt = 0; mt < 4; ++mt) {
                acc[mt][nt] = __builtin_amdgcn_mfma_f32_16x16x32_bf16(ah[mt], bh, acc[mt][nt], 0, 0, 0);
                acc[mt][nt] = __builtin_amdgcn_mfma_f32_16x16x32_bf16(al[mt], bh, acc[mt][nt], 0, 0, 0);
                acc[mt][nt] = __builtin_amdgcn_mfma_f32_16x16x32_bf16(ah[mt], bl, acc[mt][nt], 0, 0, 0);
            }
        }
    }

    unsigned short* To = Tb + (long)(g * 8 + e) * 65536 + kh * 8192;
#pragma unroll
    for (int mt = 0; mt < 4; ++mt)
#pragma unroll
        for (int nt = 0; nt < 8; ++nt)
#pragma unroll
            for (int r = 0; r < 4; ++r) {
                const int n = mt * 16 + quad * 4 + r;
                const int d = nt * 16 + col;
                To[n * 128 + d] = rne_bf16(acc[mt][nt][r]);
            }
}

// ---------------------------------------------------------------------------
// K2b: he[(g,e),f] = sum_K T[(g,e)][K] * Q[f][K].  256 K-slice blocks x 512.
// Pure streaming MFMA, no LDS/barriers.  P[s][(ge)*32+f].
// ---------------------------------------------------------------------------
__global__ __launch_bounds__(512) void k_he(
    const unsigned short* __restrict__ Tb,
    const unsigned short* __restrict__ qhi, const unsigned short* __restrict__ qlo,
    float* __restrict__ P)
{
    const int tid = threadIdx.x;
    const int s = blockIdx.x;
    const long K0 = (long)s * 256;
    const int lane = tid & 63, wid = tid >> 6;     // 0..7
    const int quad = lane >> 4, col = lane & 15;

    f32x4 acc[2][2];
#pragma unroll
    for (int mt = 0; mt < 2; ++mt)
#pragma unroll
        for (int nt = 0; nt < 2; ++nt)
#pragma unroll
            for (int r = 0; r < 4; ++r) acc[mt][nt][r] = 0.f;

    for (int ks = 0; ks < 8; ++ks) {
        const long ko = K0 + ks * 32 + quad * 8;
        short8 t[2];
#pragma unroll
        for (int mt = 0; mt < 2; ++mt) {
            const int ge = (wid * 2 + mt) * 16 + col;
            t[mt] = *(const short8*)(Tb + (long)ge * 65536 + ko);
        }
#pragma unroll
        for (int nt = 0; nt < 2; ++nt) {
            const int f = nt * 16 + col;
            short8 qh = *(const short8*)(qhi + (long)f * 65536 + ko);
            short8 ql = *(const short8*)(qlo + (long)f * 65536 + ko);
#pragma unroll
            for (int mt = 0; mt < 2; ++mt) {
                acc[mt][nt] = __builtin_amdgcn_mfma_f32_16x16x32_bf16(t[mt], qh, acc[mt][nt], 0, 0, 0);
                acc[mt][nt] = __builtin_amdgcn_mfma_f32_16x16x32_bf16(t[mt], ql, acc[mt][nt], 0, 0, 0);
            }
        }
    }

    float* Pb = P + s * 8192;
#pragma unroll
    for (int mt = 0; mt < 2; ++mt)
#pragma unroll
        for (int nt = 0; nt < 2; ++nt)
#pragma unroll
            for (int r = 0; r < 4; ++r) {
                const int ge = (wid * 2 + mt) * 16 + quad * 4 + r;
                const int f = nt * 16 + col;
                Pb[ge * 32 + f] = acc[mt][nt][r];
            }
}

// ---------------------------------------------------------------------------
// K2c: He[i] = sum_s P[s][i].  256 blocks x 256.
// Block b reduces i in [b*32, b*32+32); lanes coalesced over i, 8 s-groups.
// ---------------------------------------------------------------------------
__global__ __launch_bounds__(256) void k_hred(const float* __restrict__ P,
                                              float* __restrict__ He)
{
    __shared__ float r[256];
    const int b = blockIdx.x;
    const int tid = threadIdx.x;
    const int li = tid & 31, s0 = tid >> 5;
    const int i = b * 32 + li;
    float a0 = 0.f, a1 = 0.f, a2 = 0.f, a3 = 0.f;
    for (int k = 0; k < 32; k += 4) {
        a0 += P[(s0 + (k + 0) * 8) * 8192 + i];
        a1 += P[(s0 + (k + 1) * 8) * 8192 + i];
        a2 += P[(s0 + (k + 2) * 8) * 8192 + i];
        a3 += P[(s0 + (k + 3) * 8) * 8192 + i];
    }
    r[s0 * 32 + li] = (a0 + a1) + (a2 + a3);
    __syncthreads();
    if (tid < 32) {
        float s = 0.f;
#pragma unroll
        for (int q = 0; q < 8; ++q) s += r[q * 32 + tid];
        He[b * 32 + tid] = s;
    }
}

// ---------------------------------------------------------------------------
// K3: logits[f][g] = relu(he + b1) @ w2 + b2 ; att = softmax over g.
// 1 block x 1024 thr (tid = f*32+g); shuffle-parallel softmax within each
// 32-lane g-group.  He layout: [(g*8+e)*32 + f].
// ---------------------------------------------------------------------------
__global__ void k_soft(const float* __restrict__ He, const float* __restrict__ b1,
                       const float* __restrict__ w2, const float* __restrict__ b2,
                       float* __restrict__ att)
{
    const int tid = threadIdx.x;       // 1024 = f*32+g
    const int f = tid >> 5, g = tid & 31;
    float s = b2[0];
#pragma unroll
    for (int e = 0; e < 8; ++e)
        s += fmaxf(He[(g * 8 + e) * 32 + f] + b1[e], 0.f) * w2[e];
    float mx = s;
#pragma unroll
    for (int m = 16; m >= 1; m >>= 1) mx = fmaxf(mx, __shfl_xor(mx, m));
    float ex = expf(s - mx);
    float sum = ex;
#pragma unroll
    for (int m = 16; m >= 1; m >>= 1) sum += __shfl_xor(sum, m);
    att[f * 32 + g] = ex / sum;
}

// ---------------------------------------------------------------------------
// K4: Z[j,n,dout] = sum_{kh,d} V16[j,kh,n,d] * w3q[dout, kh*128+d] via MFMA.
// grid (j=32, dh=2): 64 blocks, 4 waves (wave = n-tile), 4 dout-tiles each.
// ---------------------------------------------------------------------------
__global__ __launch_bounds__(256) void k_z(
    const unsigned short* __restrict__ V16, const unsigned short* __restrict__ w3q,
    float* __restrict__ Z)
{
    __shared__ __align__(16) unsigned short sA[64 * 136];
    __shared__ __align__(16) unsigned short sB[64 * 136];
    const int tid = threadIdx.x;
    const int j = blockIdx.x, dh = blockIdx.y;
    const int lane = tid & 63, wid = tid >> 6;
    const int quad = lane >> 4, col = lane & 15;

    f32x4 acc[4];
#pragma unroll
    for (int dt = 0; dt < 4; ++dt)
#pragma unroll
        for (int r = 0; r < 4; ++r) acc[dt][r] = 0.f;

    for (int kh = 0; kh < 8; ++kh) {
        __syncthreads();
        {
            const unsigned short* plane = V16 + (long)(j * 8 + kh) * 8192;
#pragma unroll
            for (int it = 0; it < 4; ++it) {
                const int gdx = it * 256 + tid;
                const int n = gdx >> 4, c = gdx & 15;
                *(short8*)(sA + n * 136 + c * 8) = *(const short8*)(plane + n * 128 + c * 8);
            }
#pragma unroll
            for (int it = 0; it < 4; ++it) {
                const int gdx = it * 256 + tid;
                const int row = gdx >> 4, c = gdx & 15;
                *(short8*)(sB + row * 136 + c * 8) =
                    *(const short8*)(w3q + (dh * 64 + row) * 1024 + kh * 128 + c * 8);
            }
        }
        __syncthreads();

#pragma unroll
        for (int ks = 0; ks < 4; ++ks) {
            short8 a = *(const short8*)(sA + (wid * 16 + col) * 136 + ks * 32 + quad * 8);
#pragma unroll
            for (int dt = 0; dt < 4; ++dt) {
                short8 b = *(const short8*)(sB + (dt * 16 + col) * 136 + ks * 32 + quad * 8);
                acc[dt] = __builtin_amdgcn_mfma_f32_16x16x32_bf16(a, b, acc[dt], 0, 0, 0);
            }
        }
    }

#pragma unroll
    for (int dt = 0; dt < 4; ++dt)
#pragma unroll
        for (int r = 0; r < 4; ++r) {
            const int n = wid * 16 + quad * 4 + r;
            const int dout = dh * 64 + dt * 16 + col;
            Z[(j * 64 + n) * 128 + dout] = acc[dt][r];
        }
}

// ---------------------------------------------------------------------------
// K5: grid (n=64, th=2). y1 = relu(b3 + att@Z) per t-half; out = y1@w4^T+b4.
// All phase-2 operands in LDS (w4 half staged up front).
// ---------------------------------------------------------------------------
__global__ __launch_bounds__(256) void k_y(
    const float* __restrict__ Z, const float* __restrict__ att,
    const float* __restrict__ b3, const float* __restrict__ w4,
    const float* __restrict__ b4, float* __restrict__ out)
{
    __shared__ __align__(16) float Zs[32 * 128];
    __shared__ float atts[1024];
    __shared__ __align__(16) float y1s[32 * 132];
    __shared__ __align__(16) float w4s[48 * 132];
    const int n = blockIdx.x;
    const int t0 = blockIdx.y * 48;
    const int tid = threadIdx.x;

#pragma unroll
    for (int it = 0; it < 4; ++it) {
        const int gdx = it * 256 + tid;
        const int j = gdx >> 5, c = gdx & 31;
        *(f32x4*)(Zs + j * 128 + c * 4) = *(const f32x4*)(Z + j * 8192 + n * 128 + c * 4);
        atts[gdx] = att[gdx];
    }
#pragma unroll
    for (int it = 0; it < 6; ++it) {     // stage w4 half: 48 rows x 32 f32x4
        const int gdx = it * 256 + tid;
        const int row = gdx >> 5, c = gdx & 31;
        *(f32x4*)(w4s + row * 132 + c * 4) = *(const f32x4*)(w4 + (t0 + row) * 128 + c * 4);
    }
    __syncthreads();

    {   // phase 1: thread = (f, dout/16-group)
        const int ff = tid >> 3, l8 = tid & 7;
        f32x4 a4[4];
#pragma unroll
        for (int v = 0; v < 4; ++v) a4[v] = *(const f32x4*)(b3 + l8 * 16 + v * 4);
        for (int j = 0; j < 32; ++j) {
            const float a = atts[ff * 32 + j];
#pragma unroll
            for (int v = 0; v < 4; ++v) {
                f32x4 z = *(const f32x4*)(Zs + j * 128 + l8 * 16 + v * 4);
                a4[v].x += a * z.x; a4[v].y += a * z.y;
                a4[v].z += a * z.z; a4[v].w += a * z.w;
            }
        }
#pragma unroll
        for (int v = 0; v < 4; ++v) {
            f32x4 r;
            r.x = fmaxf(a4[v].x, 0.f); r.y = fmaxf(a4[v].y, 0.f);
            r.z = fmaxf(a4[v].z, 0.f); r.w = fmaxf(a4[v].w, 0.f);
            *(f32x4*)(y1s + ff * 132 + l8 * 16 + v * 4) = r;
        }
    }
    __syncthreads();

#pragma unroll
    for (int it = 0; it < 6; ++it) {     // phase 2: o = tl*32+f over 48 t's
        const int o = it * 256 + tid;
        const int tl = o >> 5, ff = o & 31;
        float s = b4[t0 + tl];
        const float* w4r = w4s + tl * 132;
        const float* y1r = y1s + ff * 132;
#pragma unroll 8
        for (int d4 = 0; d4 < 32; ++d4) {
            f32x4 w = *(const f32x4*)(w4r + d4 * 4);
            f32x4 y = *(const f32x4*)(y1r + d4 * 4);
            s += y.x * w.x + y.y * w.y + y.z * w.z + y.w * w.w;
        }
        out[n * 3072 + (t0 + tl) * 32 + ff] = s;
    }
}

// ---------------------------------------------------------------------------
extern "C" void kernel_launch(void* const* d_in, const int* in_sizes, int n_in,
                              void* d_out, int out_size, void* d_ws, size_t ws_size,
                              hipStream_t stream)
{
    const float* x  = (const float*)d_in[0];
    const float* Wq = (const float*)d_in[1];
    const float* Wk = (const float*)d_in[2];
    const float* Wv = (const float*)d_in[3];
    const float* bq = (const float*)d_in[4];
    const float* bk = (const float*)d_in[5];
    const float* bv = (const float*)d_in[6];
    const float* w1 = (const float*)d_in[7];
    const float* b1 = (const float*)d_in[8];
    const float* w2 = (const float*)d_in[9];
    const float* b2 = (const float*)d_in[10];
    const float* w3 = (const float*)d_in[11];
    const float* b3 = (const float*)d_in[12];
    const float* w4 = (const float*)d_in[13];
    const float* b4 = (const float*)d_in[14];

    float* out = (float*)d_out;
    char*  wb  = (char*)d_ws;
    unsigned short* qhi = (unsigned short*)(wb + 0x0000000);   // 4 MB
    unsigned short* qlo = (unsigned short*)(wb + 0x0400000);   // 4 MB
    unsigned short* V16 = (unsigned short*)(wb + 0x0800000);   // 4 MB
    unsigned short* ktH = (unsigned short*)(wb + 0x0C00000);   // 4 MB
    unsigned short* ktL = (unsigned short*)(wb + 0x1000000);   // 4 MB
    unsigned short* Tb  = (unsigned short*)(wb + 0x1400000);   // 32 MB
    float*          Pp  = (float*)        (wb + 0x3400000);    // 8 MB
    float*          He  = (float*)        (wb + 0x3C00000);    // 32 KB
    unsigned short* Ahi = (unsigned short*)(wb + 0x3C10000);   // 384 KB
    unsigned short* Alo = (unsigned short*)(wb + 0x3C70000);   // 384 KB
    unsigned short* Wth = (unsigned short*)(wb + 0x3CD0000);   // 576 KB
    unsigned short* Wtl = (unsigned short*)(wb + 0x3D60000);   // 576 KB
    unsigned short* w1h = (unsigned short*)(wb + 0x3DF0000);   // 512 KB
    unsigned short* w1l = (unsigned short*)(wb + 0x3E70000);   // 512 KB
    unsigned short* w3q = (unsigned short*)(wb + 0x3EF0000);   // 256 KB
    float*          Zb  = (float*)        (wb + 0x3F30000);    // 1 MB (end ~64.2 MB)
    float* att = out + 196608;

    k_prep <<<136, 256, 0, stream>>>(x, Wq, Wk, Wv, w1, w3,
                                     Ahi, Alo, Wth, Wtl, w1h, w1l, w3q);
    k_qkvg <<<dim3(32, 2, 24), 256, 0, stream>>>(Ahi, Alo, Wth, Wtl, bq, bk, bv,
                                                 qhi, qlo, ktH, ktL, V16);
    k_t    <<<dim3(256, 2), 256, 0, stream>>>(ktH, ktL, w1h, w1l, Tb);
    k_he   <<<256, 512, 0, stream>>>(Tb, qhi, qlo, Pp);
    k_hred <<<256, 256, 0, stream>>>(Pp, He);
    k_soft <<<1, 1024, 0, stream>>>(He, b1, w2, b2, att);
    k_z    <<<dim3(32, 2), 256, 0, stream>>>(V16, w3q, Zb);
    k_y    <<<dim3(64, 2), 256, 0, stream>>>(Zb, att, b3, w4, b4, out);
}